// Round 2
// baseline (493.481 us; speedup 1.0000x reference)
//
#include <hip/hip_runtime.h>
#include <hip/hip_bf16.h>
#include <stdint.h>

#define N_NODES 100000
#define N_EDGES 1200000
#define IN_CH 64
#define HID 16
#define OUT_CH 64

typedef __hip_bfloat16 bf16;

__device__ __forceinline__ float b2f(bf16 v) { return __bfloat162float(v); }
__device__ __forceinline__ float lo_f(uint32_t p) { return __uint_as_float(p << 16); }
__device__ __forceinline__ float hi_f(uint32_t p) { return __uint_as_float(p & 0xffff0000u); }

// dtype-agnostic scalar float load: bf => bf16 array, else f32 array
__device__ __forceinline__ float loadf(const void* p, int i, int bf) {
    return bf ? b2f(((const bf16*)p)[i]) : ((const float*)p)[i];
}
// index load: i64 => low word of int64 (little-endian), else int32
__device__ __forceinline__ int loadi(const int* p, int i, int i64) {
    return i64 ? p[2 * i] : p[i];
}

// Detect dtypes; fold layer-1 edge projection through W1l.
// wc[0..47] = W1e @ W1l (3x16), wc[48..63] = b1e @ W1l
__global__ void k_prep(const void* __restrict__ x, const int* __restrict__ ei,
                       const void* __restrict__ W1e, const void* __restrict__ b1e,
                       const void* __restrict__ W1l, float* __restrict__ wc,
                       int* __restrict__ flags) {
    __shared__ int s_bf;
    if (threadIdx.x == 0) {
        const uint16_t* u = (const uint16_t*)x;
        int cnt = 0;
        for (int i = 0; i < 64; ++i) {
            int e = (u[i] >> 7) & 0xff;
            cnt += (e >= 100 && e <= 140);
        }
        int bf = (cnt >= 50);
        const uint32_t* w = (const uint32_t*)ei;
        int z = 0;
        for (int i = 1; i < 64; i += 2) z += (w[i] == 0u);
        flags[0] = bf;
        flags[1] = (z >= 16);
        s_bf = bf;
    }
    __syncthreads();
    int bf = s_bf;
    int j = threadIdx.x;
    if (j >= HID) return;
    for (int r = 0; r < 3; ++r) {
        float s = 0.f;
        for (int k = 0; k < IN_CH; ++k)
            s += loadf(W1e, r * IN_CH + k, bf) * loadf(W1l, k * HID + j, bf);
        wc[r * HID + j] = s;
    }
    float s = 0.f;
    for (int k = 0; k < IN_CH; ++k)
        s += loadf(b1e, k, bf) * loadf(W1l, k * HID + j, bf);
    wc[3 * HID + j] = s;
}

// y = x @ W1l  (N x 16), 16 threads per row
__global__ void __launch_bounds__(256) k_y(const void* __restrict__ x,
                                           const void* __restrict__ W1l,
                                           const int* __restrict__ flags,
                                           float* __restrict__ y) {
    __shared__ float w[IN_CH * HID];  // 4 KB
    int bf = flags[0];
    for (int t = threadIdx.x; t < IN_CH * HID; t += 256) w[t] = loadf(W1l, t, bf);
    __syncthreads();
    int tid = blockIdx.x * 256 + threadIdx.x;
    int row = tid >> 4;
    if (row >= N_NODES) return;
    int c = tid & 15;
    float acc = 0.f;
    if (bf) {
        const uint32_t* xr = (const uint32_t*)x + (size_t)row * (IN_CH / 2);
#pragma unroll
        for (int k2 = 0; k2 < IN_CH / 2; ++k2) {
            uint32_t p = xr[k2];
            acc += lo_f(p) * w[(2 * k2) * HID + c] + hi_f(p) * w[(2 * k2 + 1) * HID + c];
        }
    } else {
        const float* xr = (const float*)x + (size_t)row * IN_CH;
#pragma unroll
        for (int k = 0; k < IN_CH; ++k) acc += xr[k] * w[k * HID + c];
    }
    y[row * HID + c] = acc;
}

// Edge pass 1: sy[dst] += y[src]; sa[dst] += edge_attr; deg[dst] += 1
__global__ void __launch_bounds__(256) k_edge1(const int* __restrict__ ei,
                                               const void* __restrict__ ea,
                                               const int* __restrict__ flags,
                                               const float* __restrict__ y,
                                               float* __restrict__ sy,
                                               float* __restrict__ sa,
                                               float* __restrict__ deg) {
    int tid = blockIdx.x * 256 + threadIdx.x;
    int e = tid >> 4;
    if (e >= N_EDGES) return;
    int c = tid & 15;
    int i64 = flags[1], bf = flags[0];
    int src = loadi(ei, e, i64);
    int dst = loadi(ei, N_EDGES + e, i64);
    atomicAdd(&sy[dst * HID + c], y[src * HID + c]);
    if (c < 3)
        atomicAdd(&sa[dst * 3 + c], loadf(ea, e * 3 + c, bf));
    else if (c == 3)
        atomicAdd(&deg[dst], 1.0f);
}

// h = relu((sy + sa@wc + deg*bc)/max(deg,1) + b1l + b1r + x@W1r)   [in-place over sy]
__global__ void __launch_bounds__(256) k_h(float* __restrict__ syh,
                                           const float* __restrict__ sa,
                                           const float* __restrict__ deg,
                                           const void* __restrict__ x,
                                           const void* __restrict__ W1r,
                                           const void* __restrict__ b1l,
                                           const void* __restrict__ b1r,
                                           const float* __restrict__ wc,
                                           const int* __restrict__ flags) {
    __shared__ float wr[IN_CH * HID];
    __shared__ float bsum[HID];
    int bf = flags[0];
    for (int t = threadIdx.x; t < IN_CH * HID; t += 256) wr[t] = loadf(W1r, t, bf);
    if (threadIdx.x < HID)
        bsum[threadIdx.x] = loadf(b1l, threadIdx.x, bf) + loadf(b1r, threadIdx.x, bf);
    __syncthreads();
    int tid = blockIdx.x * 256 + threadIdx.x;
    int i = tid >> 4;
    if (i >= N_NODES) return;
    int c = tid & 15;
    float zc = 0.f;
    if (bf) {
        const uint32_t* xr = (const uint32_t*)x + (size_t)i * (IN_CH / 2);
#pragma unroll
        for (int k2 = 0; k2 < IN_CH / 2; ++k2) {
            uint32_t p = xr[k2];
            zc += lo_f(p) * wr[(2 * k2) * HID + c] + hi_f(p) * wr[(2 * k2 + 1) * HID + c];
        }
    } else {
        const float* xr = (const float*)x + (size_t)i * IN_CH;
#pragma unroll
        for (int k = 0; k < IN_CH; ++k) zc += xr[k] * wr[k * HID + c];
    }
    float d = deg[i];
    float inv = 1.0f / fmaxf(d, 1.0f);
    float s0 = sa[i * 3 + 0], s1 = sa[i * 3 + 1], s2 = sa[i * 3 + 2];
    float acc = syh[i * HID + c] + s0 * wc[c] + s1 * wc[HID + c] + s2 * wc[2 * HID + c] +
                d * wc[3 * HID + c];
    float v = acc * inv + bsum[c] + zc;
    syh[i * HID + c] = fmaxf(v, 0.0f);
}

// Edge pass 2: sh[dst] += h[src]
__global__ void __launch_bounds__(256) k_edge2(const int* __restrict__ ei,
                                               const int* __restrict__ flags,
                                               const float* __restrict__ h,
                                               float* __restrict__ sh) {
    int tid = blockIdx.x * 256 + threadIdx.x;
    int e = tid >> 4;
    if (e >= N_EDGES) return;
    int c = tid & 15;
    int i64 = flags[1];
    int src = loadi(ei, e, i64);
    int dst = loadi(ei, N_EDGES + e, i64);
    atomicAdd(&sh[dst * HID + c], h[src * HID + c]);
}

// out = ((sh + sa@W2e + deg*b2e)/max(deg,1)) @ W2l + h @ W2r + b2l + b2r
__global__ void __launch_bounds__(256) k_out(const float* __restrict__ sh,
                                             const float* __restrict__ sa,
                                             const float* __restrict__ deg,
                                             const float* __restrict__ h,
                                             const void* __restrict__ W2l,
                                             const void* __restrict__ b2l,
                                             const void* __restrict__ W2r,
                                             const void* __restrict__ b2r,
                                             const void* __restrict__ W2e,
                                             const void* __restrict__ b2e,
                                             const int* __restrict__ flags,
                                             void* __restrict__ out) {
    __shared__ float wl[HID * OUT_CH];
    __shared__ float wr[HID * OUT_CH];
    __shared__ float we[3 * HID];
    __shared__ float be[HID];
    __shared__ float bb[OUT_CH];
    int bf = flags[0];
    for (int t = threadIdx.x; t < HID * OUT_CH; t += 256) {
        wl[t] = loadf(W2l, t, bf);
        wr[t] = loadf(W2r, t, bf);
    }
    if (threadIdx.x < 3 * HID) we[threadIdx.x] = loadf(W2e, threadIdx.x, bf);
    if (threadIdx.x < HID) be[threadIdx.x] = loadf(b2e, threadIdx.x, bf);
    if (threadIdx.x < OUT_CH)
        bb[threadIdx.x] = loadf(b2l, threadIdx.x, bf) + loadf(b2r, threadIdx.x, bf);
    __syncthreads();
    int tid = blockIdx.x * 256 + threadIdx.x;
    int i = tid >> 6;
    if (i >= N_NODES) return;
    int j = tid & 63;
    float d = deg[i];
    float inv = 1.0f / fmaxf(d, 1.0f);
    float s0 = sa[i * 3 + 0], s1 = sa[i * 3 + 1], s2 = sa[i * 3 + 2];
    float o = bb[j];
#pragma unroll
    for (int c = 0; c < HID; ++c) {
        float t = (sh[i * HID + c] + s0 * we[c] + s1 * we[HID + c] + s2 * we[2 * HID + c] +
                   d * be[c]) * inv;
        o += t * wl[c * OUT_CH + j];
        o += h[i * HID + c] * wr[c * OUT_CH + j];
    }
    if (bf)
        ((bf16*)out)[i * OUT_CH + j] = __float2bfloat16(o);
    else
        ((float*)out)[i * OUT_CH + j] = o;
}

extern "C" void kernel_launch(void* const* d_in, const int* in_sizes, int n_in,
                              void* d_out, int out_size, void* d_ws, size_t ws_size,
                              hipStream_t stream) {
    const void* x   = d_in[0];
    const int*  ei  = (const int*)d_in[1];
    const void* ea  = d_in[2];
    const void* W1l = d_in[3];
    const void* b1l = d_in[4];
    const void* W1r = d_in[5];
    const void* b1r = d_in[6];
    const void* W1e = d_in[7];
    const void* b1e = d_in[8];
    const void* W2l = d_in[9];
    const void* b2l = d_in[10];
    const void* W2r = d_in[11];
    const void* b2r = d_in[12];
    const void* W2e = d_in[13];
    const void* b2e = d_in[14];

    float* ws = (float*)d_ws;
    const size_t N16 = (size_t)N_NODES * HID;
    float* bufA = ws;                          // y, then (re-zeroed) sh
    float* bufB = bufA + N16;                  // sy, then h (in-place)
    float* sa   = bufB + N16;                  // N*3  (zeroed)
    float* deg  = sa + (size_t)N_NODES * 3;    // N    (zeroed)
    float* wc   = deg + N_NODES;               // 64
    int*   flags = (int*)(wc + 64);            // 2
    // total: 2*N16 + 4*N + 66 floats ~= 14.4 MB

    // zero sy, sa, deg (contiguous)
    hipMemsetAsync(bufB, 0, (N16 + 4 * (size_t)N_NODES) * sizeof(float), stream);

    k_prep<<<1, 64, 0, stream>>>(x, ei, W1e, b1e, W1l, wc, flags);
    k_y<<<(N_NODES * 16 + 255) / 256, 256, 0, stream>>>(x, W1l, flags, bufA);
    k_edge1<<<(N_EDGES * 16 + 255) / 256, 256, 0, stream>>>(ei, ea, flags, bufA, bufB, sa, deg);
    k_h<<<(N_NODES * 16 + 255) / 256, 256, 0, stream>>>(bufB, sa, deg, x, W1r, b1l, b1r, wc, flags);
    // bufA (y) is dead after k_edge1; re-zero it to become sh
    hipMemsetAsync(bufA, 0, N16 * sizeof(float), stream);
    k_edge2<<<(N_EDGES * 16 + 255) / 256, 256, 0, stream>>>(ei, flags, bufB, bufA);
    k_out<<<(N_NODES * 64 + 255) / 256, 256, 0, stream>>>(bufA, sa, deg, bufB, W2l, b2l,
                                                          W2r, b2r, W2e, b2e, flags, d_out);
}